// Round 1
// baseline (24125.613 us; speedup 1.0000x reference)
//
#include <hip/hip_runtime.h>
#include <math.h>

// 2-layer LSTM decoder, H=100, T=8192 encode steps + F=1024 future steps.
// Two persistent blocks (2 CUs):
//   block 0 (A): layer-1 LSTM chain. w_hh1 row in registers (thread j<400).
//   block 1 (B): layer-2 LSTM chain + y = h2.w_lin + b. w_ih2/w_hh2 rows in regs.
// A->B: h1 ring buffer in d_ws + monotonic release/acquire counters (agent scope,
// cross-XCD safe). Counters are monotonic and <= 9217, so 0xAA poison sanitizes to 0.
// Future phase: B publishes y back to A (ping-pong).

#define HH 100
#define G4 400
#define NT 448            // 7 waves; rows 0..399 active
#define OFF_BPROG 128
#define OFF_YPROG 256
#define OFF_YSLOT 512
#define OFF_RING  8192
#define SPIN_CAP  20000000u   // ~300x margin over any legit wait; hang insurance

__device__ __forceinline__ float sigm(float x) { return 1.0f / (1.0f + expf(-x)); }
// poison-immune read of a monotonic counter (max legit value ~9217)
__device__ __forceinline__ unsigned san(unsigned v) { return v > 0x00FFFFFFu ? 0u : v; }

extern "C" __global__ void __launch_bounds__(NT, 2)
decoder_kernel(const float* __restrict__ input,
               const float* __restrict__ enc_h,
               const float* __restrict__ enc_c,
               const float* __restrict__ w_ih1,
               const float* __restrict__ w_hh1,
               const float* __restrict__ b_ih1,
               const float* __restrict__ b_hh1,
               const float* __restrict__ w_ih2,
               const float* __restrict__ w_hh2,
               const float* __restrict__ b_ih2,
               const float* __restrict__ b_hh2,
               const float* __restrict__ w_lin,
               const float* __restrict__ b_lin,
               float* __restrict__ out,
               char* __restrict__ ws,
               int T, int F, int ring)
{
    const int tid = threadIdx.x;
    unsigned* a_prog = (unsigned*)(ws);             // A: steps published
    unsigned* b_prog = (unsigned*)(ws + OFF_BPROG); // B: steps consumed (flow control)
    unsigned* y_prog = (unsigned*)(ws + OFF_YPROG); // B: y values published
    float* y_slot    = (float*)(ws + OFF_YSLOT);    // y(T-1+k) at index k
    float* ring_base = (float*)(ws + OFF_RING);     // ring slots of 100 floats
    const int rmask = ring - 1;
    const int TOT = T + F;

    if (blockIdx.x == 0) {
        // ================= Block A: layer-1 LSTM =================
        __shared__ __align__(16) float h1s[HH];
        __shared__ float g1[G4];
        __shared__ float xsh;
        float wr[HH];
        float wx = 0.f, bias = 0.f;
        if (tid < G4) {
            wx   = w_ih1[tid];
            bias = b_ih1[tid] + b_hh1[tid];
            #pragma unroll
            for (int k = 0; k < HH; ++k) wr[k] = w_hh1[tid * HH + k];
        }
        float c1 = 0.f;
        if (tid < HH) { h1s[tid] = enc_h[tid]; c1 = enc_c[tid]; }
        __syncthreads();

        unsigned cb = 0, cy = 0;
        for (int t = 0; t < TOT; ++t) {
            float x;
            if (t < T) {
                x = input[t];
            } else {
                // future phase: x = y(t-1), published by B as y_slot[t-T]
                if (tid == 0) {
                    unsigned need = (unsigned)(t - T + 1);
                    unsigned spins = 0;
                    while (cy < need) {
                        cy = san(__hip_atomic_load(y_prog, __ATOMIC_ACQUIRE, __HIP_MEMORY_SCOPE_AGENT));
                        if (++spins > SPIN_CAP) break;
                    }
                    xsh = y_slot[t - T];
                }
                __syncthreads();
                x = xsh;
            }
            // flow control: don't overwrite ring slot until B consumed it
            if (tid == 0 && t >= ring) {
                unsigned need = (unsigned)(t - ring + 1);
                unsigned spins = 0;
                while (cb < need) {
                    cb = san(__hip_atomic_load(b_prog, __ATOMIC_ACQUIRE, __HIP_MEMORY_SCOPE_AGENT));
                    if (++spins > SPIN_CAP) break;
                }
            }
            if (tid < G4) {
                float a0=0.f, a1=0.f, a2=0.f, a3=0.f;
                #pragma unroll
                for (int k = 0; k < HH; k += 4) {
                    a0 = fmaf(wr[k+0], h1s[k+0], a0);
                    a1 = fmaf(wr[k+1], h1s[k+1], a1);
                    a2 = fmaf(wr[k+2], h1s[k+2], a2);
                    a3 = fmaf(wr[k+3], h1s[k+3], a3);
                }
                float acc = fmaf(x, wx, bias) + ((a0+a1)+(a2+a3));
                g1[tid] = (tid / HH == 2) ? tanhf(acc) : sigm(acc);  // i,f,o:sigmoid g:tanh
            }
            __syncthreads();
            if (tid < HH) {
                float gi = g1[tid], gf = g1[tid+HH], gg = g1[tid+2*HH], go = g1[tid+3*HH];
                c1 = fmaf(gf, c1, gi*gg);
                float h = go * tanhf(c1);
                h1s[tid] = h;
                ring_base[(size_t)(t & rmask)*HH + tid] = h;
            }
            __syncthreads();
            if (tid == 0) {
                __threadfence();
                __hip_atomic_store(a_prog, (unsigned)(t+1), __ATOMIC_RELEASE, __HIP_MEMORY_SCOPE_AGENT);
            }
        }
    } else {
        // ================= Block B: layer-2 LSTM + output =================
        __shared__ __align__(16) float h1b[HH];
        __shared__ __align__(16) float h2s[HH];
        __shared__ float g2[G4];
        __shared__ float yp[HH];
        float wi[HH], wh[HH];
        float bias = 0.f, wl = 0.f;
        if (tid < G4) {
            bias = b_ih2[tid] + b_hh2[tid];
            #pragma unroll
            for (int k = 0; k < HH; ++k) wi[k] = w_ih2[tid*HH + k];
            #pragma unroll
            for (int k = 0; k < HH; ++k) wh[k] = w_hh2[tid*HH + k];
        }
        float c2 = 0.f;
        float bl = b_lin[0];
        if (tid < HH) { h2s[tid] = 0.f; wl = w_lin[tid]; }
        __syncthreads();

        unsigned ca = 0;
        for (int t = 0; t < TOT; ++t) {
            if (tid == 0) {
                unsigned need = (unsigned)(t+1);
                unsigned spins = 0;
                while (ca < need) {
                    ca = san(__hip_atomic_load(a_prog, __ATOMIC_ACQUIRE, __HIP_MEMORY_SCOPE_AGENT));
                    if (++spins > SPIN_CAP) break;
                }
            }
            __syncthreads();
            if (tid < HH/4) {   // copy h1(t) slot -> LDS (25 x float4)
                const float4* s4 = (const float4*)(ring_base + (size_t)(t & rmask)*HH);
                ((float4*)h1b)[tid] = s4[tid];
            }
            __syncthreads();
            if (tid < G4) {
                float a0=0.f, a1=0.f, a2=0.f, a3=0.f;
                #pragma unroll
                for (int k = 0; k < HH; k += 4) {
                    a0 = fmaf(wi[k+0], h1b[k+0], a0);
                    a1 = fmaf(wi[k+1], h1b[k+1], a1);
                    a2 = fmaf(wi[k+2], h1b[k+2], a2);
                    a3 = fmaf(wi[k+3], h1b[k+3], a3);
                }
                #pragma unroll
                for (int k = 0; k < HH; k += 4) {
                    a0 = fmaf(wh[k+0], h2s[k+0], a0);
                    a1 = fmaf(wh[k+1], h2s[k+1], a1);
                    a2 = fmaf(wh[k+2], h2s[k+2], a2);
                    a3 = fmaf(wh[k+3], h2s[k+3], a3);
                }
                float acc = bias + ((a0+a1)+(a2+a3));
                g2[tid] = (tid / HH == 2) ? tanhf(acc) : sigm(acc);
            }
            __syncthreads();
            if (tid < HH) {
                float gi = g2[tid], gf = g2[tid+HH], gg = g2[tid+2*HH], go = g2[tid+3*HH];
                c2 = fmaf(gf, c2, gi*gg);
                float h = go * tanhf(c2);
                h2s[tid] = h;
                yp[tid] = h * wl;
            }
            __syncthreads();
            if (tid < 64) {     // y = sum(yp) + b_lin, wave-0 reduction
                float v = yp[tid] + ((tid < HH-64) ? yp[tid+64] : 0.f);
                v += __shfl_down(v, 32);
                v += __shfl_down(v, 16);
                v += __shfl_down(v, 8);
                v += __shfl_down(v, 4);
                v += __shfl_down(v, 2);
                v += __shfl_down(v, 1);
                if (tid == 0) {
                    float y = v + bl;
                    out[t] = y;
                    if (t >= T-1) y_slot[t-(T-1)] = y;
                    __threadfence();
                    if (t >= T-1)
                        __hip_atomic_store(y_prog, (unsigned)(t-T+2), __ATOMIC_RELEASE, __HIP_MEMORY_SCOPE_AGENT);
                    __hip_atomic_store(b_prog, (unsigned)(t+1), __ATOMIC_RELEASE, __HIP_MEMORY_SCOPE_AGENT);
                }
            }
            // next iteration's first __syncthreads orders stage 5 vs h1b overwrite
        }
    }
}

extern "C" void kernel_launch(void* const* d_in, const int* in_sizes, int n_in,
                              void* d_out, int out_size, void* d_ws, size_t ws_size,
                              hipStream_t stream) {
    const float* input = (const float*)d_in[0];
    const float* enc_h = (const float*)d_in[1];
    const float* enc_c = (const float*)d_in[2];
    const float* w_ih1 = (const float*)d_in[3];
    const float* w_hh1 = (const float*)d_in[4];
    const float* b_ih1 = (const float*)d_in[5];
    const float* b_hh1 = (const float*)d_in[6];
    const float* w_ih2 = (const float*)d_in[7];
    const float* w_hh2 = (const float*)d_in[8];
    const float* b_ih2 = (const float*)d_in[9];
    const float* b_hh2 = (const float*)d_in[10];
    const float* w_lin = (const float*)d_in[11];
    const float* b_lin = (const float*)d_in[12];
    (void)n_in;

    int T = in_sizes[0];
    int F = out_size - T;
    if (F < 0) F = 0;

    // largest power-of-two ring that fits in d_ws (16384 slots > TOT disables flow control)
    int ring = 16;
    if (ws_size > (size_t)OFF_RING + 16u*HH*4u) {
        size_t max_slots = (ws_size - OFF_RING) / (HH * 4);
        while ((size_t)ring * 2 <= max_slots && ring < 16384) ring <<= 1;
    }

    decoder_kernel<<<dim3(2), dim3(NT), 0, stream>>>(
        input, enc_h, enc_c, w_ih1, w_hh1, b_ih1, b_hh1,
        w_ih2, w_hh2, b_ih2, b_hh2, w_lin, b_lin,
        (float*)d_out, (char*)d_ws, T, F, ring);
}

// Round 2
// 19704.492 us; speedup vs baseline: 1.2244x; 1.2244x over previous
//
#include <hip/hip_runtime.h>
#include <math.h>

// 2-layer LSTM decoder, H=100, T=8192 encode + F=1024 future steps, fp32.
// Three persistent blocks (3 CUs), 256 threads (4 waves) each, 2 rows/thread:
//   block 0 (A) : layer-1 recurrence. gates1 = w_ih1*x + w_hh1*h1 + b. h1 -> ring1.
//   block 1 (A2): feed-forward pre2 = w_ih2*h1 + b_ih2 + b_hh2. ring1 -> ring2.
//   block 2 (B) : layer-2 recurrence gates2 = pre2 + w_hh2*h2; y = h2.w_lin + b.
// h broadcast inside a block: h lives lane-indexed in VGPRs (hv0=h[lane],
// hv1=h[64+lane]); inner dot uses v_readlane -> SGPR operand of v_fma
// (no LDS/VMEM in the hot loop). Readlanes are shared across the 2 rows.
// Cross-CU: ring buffers in d_ws, monotonic release/acquire counters
// (agent scope). Ring reads are agent-relaxed atomic loads (sc0, L1-bypass)
// so no reliance on L1 invalidation timing. Counters monotone <= 9217, so
// 0xAA poison sanitizes to 0.

#define HH 100
#define NT 256
#define ROWS 400
#define SPIN_CAP 2000000u

#define OFF_APROG  0
#define OFF_P2PROG 128
#define OFF_BPROG  256
#define OFF_YPROG  384
#define OFF_YSLOT  512     // (F+1) floats, F<=1024 -> 4.1 KB
#define OFF_RING   16384

__device__ __forceinline__ float rl(float v, int k) {
    return __int_as_float(__builtin_amdgcn_readlane(__float_as_int(v), k));
}
__device__ __forceinline__ unsigned san(unsigned v) { return v > 0x00FFFFFFu ? 0u : v; }
__device__ __forceinline__ unsigned acq(unsigned* p) {
    return san(__hip_atomic_load(p, __ATOMIC_ACQUIRE, __HIP_MEMORY_SCOPE_AGENT));
}
__device__ __forceinline__ void rel(unsigned* p, unsigned v) {
    __hip_atomic_store(p, v, __ATOMIC_RELEASE, __HIP_MEMORY_SCOPE_AGENT);
}
__device__ __forceinline__ float ld_sc0(const float* p) {
    return __hip_atomic_load((float*)p, __ATOMIC_RELAXED, __HIP_MEMORY_SCOPE_AGENT);
}
__device__ __forceinline__ float fast_sigm(float x) {
    return __builtin_amdgcn_rcpf(1.0f + __expf(-x));
}
__device__ __forceinline__ float fast_tanh(float x) {
    // 1 - 2/(e^{2x}+1); saturates correctly at +/-inf
    return fmaf(-2.0f, __builtin_amdgcn_rcpf(1.0f + __expf(2.0f * x)), 1.0f);
}

// accA += dot(w0, h), accB += dot(w1, h); h distributed lane-indexed:
// hv0 lane k holds h[k] (k<64), hv1 lane k holds h[64+k] (k<36).
__device__ __forceinline__ void dot2rows(const float* w0, const float* w1,
                                         float hv0, float hv1,
                                         float& accA, float& accB) {
    float a0 = 0.f, a1 = 0.f, b0 = 0.f, b1 = 0.f;
    #pragma unroll
    for (int k = 0; k < 64; k += 2) {
        float h0 = rl(hv0, k), h1 = rl(hv0, k + 1);
        a0 = fmaf(w0[k],     h0, a0);
        a1 = fmaf(w0[k + 1], h1, a1);
        b0 = fmaf(w1[k],     h0, b0);
        b1 = fmaf(w1[k + 1], h1, b1);
    }
    #pragma unroll
    for (int k = 0; k < 36; k += 2) {
        float h0 = rl(hv1, k), h1 = rl(hv1, k + 1);
        a0 = fmaf(w0[64 + k],     h0, a0);
        a1 = fmaf(w0[64 + k + 1], h1, a1);
        b0 = fmaf(w1[64 + k],     h0, b0);
        b1 = fmaf(w1[64 + k + 1], h1, b1);
    }
    accA += (a0 + a1);
    accB += (b0 + b1);
}

extern "C" __global__ void __launch_bounds__(NT, 1)
decoder_kernel(const float* __restrict__ input,
               const float* __restrict__ enc_h,
               const float* __restrict__ enc_c,
               const float* __restrict__ w_ih1,
               const float* __restrict__ w_hh1,
               const float* __restrict__ b_ih1,
               const float* __restrict__ b_hh1,
               const float* __restrict__ w_ih2,
               const float* __restrict__ w_hh2,
               const float* __restrict__ b_ih2,
               const float* __restrict__ b_hh2,
               const float* __restrict__ w_lin,
               const float* __restrict__ b_lin,
               float* __restrict__ out,
               char* __restrict__ ws,
               int T, int F, int S)
{
    const int tid = threadIdx.x;
    const int l = tid & 63;
    unsigned* a_prog  = (unsigned*)(ws + OFF_APROG);
    unsigned* p2_prog = (unsigned*)(ws + OFF_P2PROG);
    unsigned* b_prog  = (unsigned*)(ws + OFF_BPROG);
    unsigned* y_prog  = (unsigned*)(ws + OFF_YPROG);
    float* y_slot = (float*)(ws + OFF_YSLOT);
    float* ring1  = (float*)(ws + OFF_RING);
    float* ring2  = ring1 + (size_t)S * HH;
    const int smask = S - 1;
    const int TOT = T + F;
    const bool has2 = tid < (ROWS - NT);   // tid < 144 owns a second row
    const int j0 = tid, j1 = NT + tid;
    const int j1s = has2 ? j1 : 0;         // safe index for inactive threads

    if (blockIdx.x == 0) {
        // ================= A: layer-1 recurrence =================
        __shared__ __align__(16) float h1s[128];
        __shared__ float g1[ROWS];
        __shared__ float xsh;
        float w0[HH], w1[HH];
        float wx0, wx1 = 0.f, bi0, bi1 = 0.f;
        wx0 = w_ih1[j0];
        bi0 = b_ih1[j0] + b_hh1[j0];
        if (has2) { wx1 = w_ih1[j1]; bi1 = b_ih1[j1] + b_hh1[j1]; }
        #pragma unroll
        for (int k = 0; k < HH; ++k) w0[k] = w_hh1[j0 * HH + k];
        #pragma unroll
        for (int k = 0; k < HH; ++k) w1[k] = w_hh1[j1s * HH + k];
        float c1 = 0.f;
        if (tid < 128) h1s[tid] = 0.f;
        __syncthreads();
        if (tid < HH) { h1s[tid] = enc_h[tid]; c1 = enc_c[tid]; }
        __syncthreads();

        unsigned cp2 = 0, cy = 0;
        for (int t = 0; t < TOT; ++t) {
            float x;
            if (t < T) {
                x = input[t];
            } else {
                if (tid == 0) {
                    unsigned need = (unsigned)(t - T + 1), s = 0;
                    while (cy < need) { cy = acq(y_prog); if (++s > SPIN_CAP) break; }
                    xsh = ld_sc0(&y_slot[t - T]);
                }
                __syncthreads();
                x = xsh;
            }
            // ring1 overwrite guard: A2 consumed slot when p2_prog advanced past it
            if (tid == 0 && t >= S) {
                unsigned need = (unsigned)(t - S + 1), s = 0;
                while (cp2 < need) { cp2 = acq(p2_prog); if (++s > SPIN_CAP) break; }
            }
            float hv0 = h1s[l];
            float hv1 = h1s[64 + l];   // lanes >=36 hold junk, never readlaned
            float accA = fmaf(x, wx0, bi0);
            float accB = fmaf(x, wx1, bi1);
            dot2rows(w0, w1, hv0, hv1, accA, accB);
            g1[j0] = (j0 >= 200 && j0 < 300) ? fast_tanh(accA) : fast_sigm(accA);
            if (has2) g1[j1] = (j1 < 300) ? fast_tanh(accB) : fast_sigm(accB);
            __syncthreads();
            if (tid < HH) {
                float gi = g1[tid], gf = g1[tid + 100], gg = g1[tid + 200], go = g1[tid + 300];
                c1 = fmaf(gf, c1, gi * gg);
                float h = go * fast_tanh(c1);
                h1s[tid] = h;
                ring1[(size_t)(t & smask) * HH + tid] = h;
            }
            __syncthreads();   // drains ring1 stores (vmcnt0 before s_barrier)
            if (tid == 0) rel(a_prog, (unsigned)(t + 1));
        }
    } else if (blockIdx.x == 1) {
        // ================= A2: pre2 = w_ih2*h1 + biases (no recurrence) =====
        float w0[HH], w1[HH];
        float bi0, bi1 = 0.f;
        bi0 = b_ih2[j0] + b_hh2[j0];
        if (has2) bi1 = b_ih2[j1] + b_hh2[j1];
        #pragma unroll
        for (int k = 0; k < HH; ++k) w0[k] = w_ih2[j0 * HH + k];
        #pragma unroll
        for (int k = 0; k < HH; ++k) w1[k] = w_ih2[j1s * HH + k];
        __syncthreads();

        unsigned ca = 0, cb = 0;
        for (int t = 0; t < TOT; ++t) {
            if (tid == 0) {
                unsigned need = (unsigned)(t + 1), s = 0;
                while (ca < need) { ca = acq(a_prog); if (++s > SPIN_CAP) break; }
                if (t >= S) {
                    need = (unsigned)(t - S + 1); s = 0;
                    while (cb < need) { cb = acq(b_prog); if (++s > SPIN_CAP) break; }
                }
            }
            __syncthreads();
            const float* rp = ring1 + (size_t)(t & smask) * HH;
            float hv0 = ld_sc0(rp + l);
            float hv1 = (l < 36) ? ld_sc0(rp + 64 + l) : 0.f;
            float accA = bi0, accB = bi1;
            dot2rows(w0, w1, hv0, hv1, accA, accB);
            float* wp = ring2 + (size_t)(t & smask) * ROWS;
            wp[j0] = accA;
            if (has2) wp[j1] = accB;
            __syncthreads();   // drains ring2 stores
            if (tid == 0) rel(p2_prog, (unsigned)(t + 1));
        }
    } else {
        // ================= B: layer-2 recurrence + output =================
        __shared__ __align__(16) float h2s[128];
        __shared__ float g2[ROWS];
        __shared__ float yp[HH];
        float w0[HH], w1[HH];
        #pragma unroll
        for (int k = 0; k < HH; ++k) w0[k] = w_hh2[j0 * HH + k];
        #pragma unroll
        for (int k = 0; k < HH; ++k) w1[k] = w_hh2[j1s * HH + k];
        float wl = 0.f, bl = b_lin[0], c2 = 0.f;
        if (tid < HH) wl = w_lin[tid];
        if (tid < 128) h2s[tid] = 0.f;
        __syncthreads();

        unsigned cp = 0;
        for (int t = 0; t < TOT; ++t) {
            if (tid == 0) {
                unsigned need = (unsigned)(t + 1), s = 0;
                while (cp < need) { cp = acq(p2_prog); if (++s > SPIN_CAP) break; }
            }
            __syncthreads();
            const float* pp = ring2 + (size_t)(t & smask) * ROWS;
            float preA = ld_sc0(pp + j0);                    // overlaps with dot below
            float preB = has2 ? ld_sc0(pp + j1) : 0.f;
            float hv0 = h2s[l];
            float hv1 = h2s[64 + l];
            float accA = 0.f, accB = 0.f;
            dot2rows(w0, w1, hv0, hv1, accA, accB);
            accA += preA; accB += preB;
            g2[j0] = (j0 >= 200 && j0 < 300) ? fast_tanh(accA) : fast_sigm(accA);
            if (has2) g2[j1] = (j1 < 300) ? fast_tanh(accB) : fast_sigm(accB);
            __syncthreads();
            if (tid < HH) {
                float gi = g2[tid], gf = g2[tid + 100], gg = g2[tid + 200], go = g2[tid + 300];
                c2 = fmaf(gf, c2, gi * gg);
                float h = go * fast_tanh(c2);
                h2s[tid] = h;
                yp[tid] = h * wl;
            }
            __syncthreads();
            if (tid < 64) {
                float v = yp[tid] + (tid < 36 ? yp[64 + tid] : 0.f);
                v += __shfl_down(v, 32);
                v += __shfl_down(v, 16);
                v += __shfl_down(v, 8);
                v += __shfl_down(v, 4);
                v += __shfl_down(v, 2);
                v += __shfl_down(v, 1);
                if (tid == 0) {
                    float y = v + bl;
                    out[t] = y;
                    if (t >= T - 1) {
                        y_slot[t - (T - 1)] = y;
                        rel(y_prog, (unsigned)(t - T + 2));   // release orders y_slot store
                    }
                    rel(b_prog, (unsigned)(t + 1));
                }
            }
        }
    }
}

extern "C" void kernel_launch(void* const* d_in, const int* in_sizes, int n_in,
                              void* d_out, int out_size, void* d_ws, size_t ws_size,
                              hipStream_t stream) {
    const float* input = (const float*)d_in[0];
    const float* enc_h = (const float*)d_in[1];
    const float* enc_c = (const float*)d_in[2];
    const float* w_ih1 = (const float*)d_in[3];
    const float* w_hh1 = (const float*)d_in[4];
    const float* b_ih1 = (const float*)d_in[5];
    const float* b_hh1 = (const float*)d_in[6];
    const float* w_ih2 = (const float*)d_in[7];
    const float* w_hh2 = (const float*)d_in[8];
    const float* b_ih2 = (const float*)d_in[9];
    const float* b_hh2 = (const float*)d_in[10];
    const float* w_lin = (const float*)d_in[11];
    const float* b_lin = (const float*)d_in[12];
    (void)n_in;

    int T = in_sizes[0];
    int F = out_size - T;
    if (F < 0) F = 0;

    // largest power-of-two ring slot count that fits both rings in d_ws
    int S = 16;
    while ((size_t)OFF_RING + (size_t)S * 2 * (HH + ROWS) * 4 <= ws_size && S < 8192)
        S <<= 1;

    decoder_kernel<<<dim3(3), dim3(NT), 0, stream>>>(
        input, enc_h, enc_c, w_ih1, w_hh1, b_ih1, b_hh1,
        w_ih2, w_hh2, b_ih2, b_hh2, w_lin, b_lin,
        (float*)d_out, (char*)d_ws, T, F, S);
}